// Round 4
// baseline (1890.677 us; speedup 1.0000x reference)
//
#include <hip/hip_runtime.h>
#include <hip/hip_bf16.h>

typedef __bf16 bf16;
typedef __bf16 bf16x8_t __attribute__((ext_vector_type(8)));
typedef __bf16 bf16x4_t __attribute__((ext_vector_type(4)));
typedef float f32x4 __attribute__((ext_vector_type(4)));

#define S_TOK 1280
#define DMODEL 1280

// ------------------------------------------------ fp32 -> bf16 convert + pad
__global__ __launch_bounds__(256) void cvt_pad_kernel(const float* __restrict__ src,
                                                      bf16* __restrict__ dst,
                                                      int rows, int scols, int dcols) {
  int idx = blockIdx.x * 256 + threadIdx.x;
  if (idx >= rows * dcols) return;
  int r = idx / dcols, c = idx - r * dcols;
  dst[idx] = (c < scols) ? (bf16)src[(size_t)r * scols + c] : (bf16)0.f;
}

// ---------------------------------------------------------------- zero fp32
__global__ __launch_bounds__(256) void zero_kernel(float* __restrict__ p, int n4) {
  int i = blockIdx.x * 256 + threadIdx.x;
  if (i < n4) ((float4*)p)[i] = make_float4(0.f, 0.f, 0.f, 0.f);
}

// ------------------------------------------------------- gelu(exact) -> bf16
__global__ __launch_bounds__(256) void gelu_cvt_kernel(const float* __restrict__ in,
                                                       bf16* __restrict__ out, int n4) {
  int i = blockIdx.x * 256 + threadIdx.x;
  if (i >= n4) return;
  float4 v = ((const float4*)in)[i];
  bf16x4_t o;
  o[0] = (bf16)(0.5f * v.x * (1.f + erff(v.x * 0.70710678f)));
  o[1] = (bf16)(0.5f * v.y * (1.f + erff(v.y * 0.70710678f)));
  o[2] = (bf16)(0.5f * v.z * (1.f + erff(v.z * 0.70710678f)));
  o[3] = (bf16)(0.5f * v.w * (1.f + erff(v.w * 0.70710678f)));
  *(bf16x4_t*)&out[(size_t)i * 4] = o;
}

// ---------------------------- bias + x*sigmoid(1.702x) + cvt (fc1 epilogue)
__global__ __launch_bounds__(256) void swish_cvt_kernel(const float* __restrict__ in,
                                                        const float* __restrict__ bias,
                                                        bf16* __restrict__ out,
                                                        int n4, int cols4) {
  int i = blockIdx.x * 256 + threadIdx.x;
  if (i >= n4) return;
  float4 v = ((const float4*)in)[i];
  int c = (i % cols4) * 4;
  const float4 bb = *(const float4*)&bias[c];
  float a0 = v.x + bb.x, a1 = v.y + bb.y, a2 = v.z + bb.z, a3 = v.w + bb.w;
  bf16x4_t o;
  o[0] = (bf16)(a0 / (1.f + __expf(-1.702f * a0)));
  o[1] = (bf16)(a1 / (1.f + __expf(-1.702f * a1)));
  o[2] = (bf16)(a2 / (1.f + __expf(-1.702f * a2)));
  o[3] = (bf16)(a3 / (1.f + __expf(-1.702f * a3)));
  *(bf16x4_t*)&out[(size_t)i * 4] = o;
}

// -------------------------- bias + rope + cvt (qkv epilogue, split-K path)
// qkvf: fp32 (S,3840) accumulated without bias; writes bf16 qkvb with rope
// applied to q,k and plain bias+cvt for v.
__global__ __launch_bounds__(256) void qkv_epi_kernel(const float* __restrict__ qkvf,
                                                      const float* __restrict__ bias,
                                                      const float* __restrict__ rotary,
                                                      bf16* __restrict__ qkvb) {
  int idx = blockIdx.x * 256 + threadIdx.x;  // S*16*40
  if (idx >= S_TOK * 16 * 40) return;
  int d = idx % 40;
  int h = (idx / 40) & 15;
  int s = idx / 640;
  float ang = rotary[s * 40 + d];
  float c = cosf(ang), sn = sinf(ang);
  size_t base = (size_t)s * 3840 + h * 80;
  // q
  float q1 = qkvf[base + d] + bias[h * 80 + d];
  float q2 = qkvf[base + d + 40] + bias[h * 80 + d + 40];
  qkvb[base + d] = (bf16)(q1 * c - q2 * sn);
  qkvb[base + d + 40] = (bf16)(q2 * c + q1 * sn);
  // k
  float k1 = qkvf[base + 1280 + d] + bias[1280 + h * 80 + d];
  float k2 = qkvf[base + 1280 + d + 40] + bias[1280 + h * 80 + d + 40];
  qkvb[base + 1280 + d] = (bf16)(k1 * c - k2 * sn);
  qkvb[base + 1280 + d + 40] = (bf16)(k2 * c + k1 * sn);
  // v
  qkvb[base + 2560 + d] = (bf16)(qkvf[base + 2560 + d] + bias[2560 + h * 80 + d]);
  qkvb[base + 2560 + d + 40] = (bf16)(qkvf[base + 2560 + d + 40] + bias[2560 + h * 80 + d + 40]);
}

// ---------------------------------------------------------------- layernorm
__global__ __launch_bounds__(256) void ln_kernel(const float* __restrict__ x,
                                                 const float* __restrict__ w,
                                                 const float* __restrict__ b,
                                                 bf16* __restrict__ out) {
  __shared__ float ls[4], ls2[4];
  int row = blockIdx.x;
  const float* xr = x + (size_t)row * DMODEL;
  float v[5];
  float s = 0.f, s2 = 0.f;
#pragma unroll
  for (int i = 0; i < 5; i++) {
    v[i] = xr[i * 256 + threadIdx.x];
    s += v[i];
    s2 += v[i] * v[i];
  }
#pragma unroll
  for (int off = 32; off; off >>= 1) {
    s += __shfl_down(s, off);
    s2 += __shfl_down(s2, off);
  }
  int wv = threadIdx.x >> 6;
  if ((threadIdx.x & 63) == 0) { ls[wv] = s; ls2[wv] = s2; }
  __syncthreads();
  float ts = ls[0] + ls[1] + ls[2] + ls[3];
  float ts2 = ls2[0] + ls2[1] + ls2[2] + ls2[3];
  float mu = ts * (1.f / DMODEL);
  float var = ts2 * (1.f / DMODEL) - mu * mu;
  float rstd = rsqrtf(var + 1e-6f);
#pragma unroll
  for (int i = 0; i < 5; i++) {
    int c = i * 256 + threadIdx.x;
    out[(size_t)row * DMODEL + c] = (bf16)((v[i] - mu) * rstd * w[c] + b[c]);
  }
}

// ---------------------------------------------------------------- rope (fallback path)
__global__ __launch_bounds__(256) void rope_kernel(bf16* __restrict__ qkv,
                                                   const float* __restrict__ rotary) {
  int idx = blockIdx.x * 256 + threadIdx.x;  // S*H*40
  if (idx >= S_TOK * 16 * 40) return;
  int d = idx % 40;
  int h = (idx / 40) & 15;
  int s = idx / (40 * 16);
  float ang = rotary[s * 40 + d];
  float c = cosf(ang), sn = sinf(ang);
#pragma unroll
  for (int qk = 0; qk < 2; ++qk) {
    bf16* base = qkv + (size_t)s * 3840 + qk * 1280 + h * 80;
    float t1 = (float)base[d], t2 = (float)base[d + 40];
    base[d] = (bf16)(t1 * c - t2 * sn);
    base[d + 40] = (bf16)(t2 * c + t1 * sn);
  }
}

// ---------------------------------------------------------------- GEMM
// C[m][n] = sum_k A[m][k] * B[n][k]  over this split's K-range.
// Split-K via blockIdx.z (Kc = K / gridDim.z, must be multiple of 32).
// Bijective XCD swizzle (T1/m204): HW round-robins dispatch index over the 8
// XCDs; remap so each XCD owns a CONTIGUOUS run of work ids (bm fastest) ->
// blocks sharing a B-panel land in the same XCD L2.
// EPI: 1 = bias -> bf16 store, 2 = atomicAdd into fp32 (bias by bz==0 only),
//      3 = bias + x*sigmoid(1.702x) -> bf16
template <int EPI, typename TB>
__global__ __launch_bounds__(256, 2) void gemm_bt(const bf16* __restrict__ A,
                                                  const TB* __restrict__ B,
                                                  const float* __restrict__ bias,
                                                  float* __restrict__ Cf,
                                                  bf16* __restrict__ Cb,
                                                  int M, int N, int K) {
  constexpr int BKP = 40;  // padded LDS k-stride
  __shared__ bf16 As[128 * BKP];
  __shared__ bf16 Bs[128 * BKP];
  const int tid = threadIdx.x;

  unsigned nwg = gridDim.x * gridDim.y * gridDim.z;
  unsigned flat = blockIdx.x + gridDim.x * (blockIdx.y + gridDim.y * blockIdx.z);
  unsigned qq = nwg >> 3, rr = nwg & 7u;
  unsigned xcd = flat & 7u, off = flat >> 3;
  unsigned wg = (xcd < rr ? xcd * (qq + 1) : rr * (qq + 1) + (xcd - rr) * qq) + off;
  const int bm = wg % gridDim.x;
  const int bn = (wg / gridDim.x) % gridDim.y;
  const int bz = wg / (gridDim.x * gridDim.y);

  const int wave = tid >> 6, lane = tid & 63;
  const int wm = (wave & 1) << 6, wn = (wave >> 1) << 6;
  const int lm = lane & 15, quad = lane >> 4;
  f32x4 acc[4][4] = {};
  const int lrow = tid >> 2;       // 0..63
  const int lcol = (tid & 3) * 8;  // 0,8,16,24
  const int arow0 = bm * 128 + lrow;
  const int brow0 = bn * 128 + lrow;
  const int Kc = K / gridDim.z;
  const int kbeg = bz * Kc;
  const int kend = kbeg + Kc;

  for (int k0 = kbeg; k0 < kend; k0 += 32) {
#pragma unroll
    for (int p = 0; p < 2; p++) {
      int ar = arow0 + p * 64;
      if (ar > M - 1) ar = M - 1;  // clamp (excess rows never stored)
      *(bf16x8_t*)&As[(p * 64 + lrow) * BKP + lcol] =
          *(const bf16x8_t*)&A[(size_t)ar * K + k0 + lcol];
      if constexpr (sizeof(TB) == 2) {
        *(bf16x8_t*)&Bs[(p * 64 + lrow) * BKP + lcol] =
            *(const bf16x8_t*)&B[(size_t)(brow0 + p * 64) * K + k0 + lcol];
      } else {
        const float* bp = (const float*)&B[(size_t)(brow0 + p * 64) * K + k0 + lcol];
        float4 f0 = *(const float4*)bp;
        float4 f1 = *(const float4*)(bp + 4);
        bf16x8_t bv;
        bv[0] = (bf16)f0.x; bv[1] = (bf16)f0.y; bv[2] = (bf16)f0.z; bv[3] = (bf16)f0.w;
        bv[4] = (bf16)f1.x; bv[5] = (bf16)f1.y; bv[6] = (bf16)f1.z; bv[7] = (bf16)f1.w;
        *(bf16x8_t*)&Bs[(p * 64 + lrow) * BKP + lcol] = bv;
      }
    }
    __syncthreads();
    bf16x8_t af[4], bfv[4];
#pragma unroll
    for (int i = 0; i < 4; i++) {
      af[i] = *(const bf16x8_t*)&As[(wm + i * 16 + lm) * BKP + quad * 8];
      bfv[i] = *(const bf16x8_t*)&Bs[(wn + i * 16 + lm) * BKP + quad * 8];
    }
#pragma unroll
    for (int i = 0; i < 4; i++)
#pragma unroll
      for (int j = 0; j < 4; j++)
        acc[i][j] = __builtin_amdgcn_mfma_f32_16x16x32_bf16(af[i], bfv[j], acc[i][j], 0, 0, 0);
    __syncthreads();
  }

#pragma unroll
  for (int j = 0; j < 4; j++) {
    int n = bn * 128 + wn + j * 16 + lm;
    float bv = (bias != nullptr && bz == 0) ? bias[n] : 0.f;
#pragma unroll
    for (int i = 0; i < 4; i++) {
      int mbase = bm * 128 + wm + i * 16 + quad * 4;
#pragma unroll
      for (int r = 0; r < 4; r++) {
        int m = mbase + r;
        if (m >= M) continue;
        float v = acc[i][j][r] + bv;
        size_t idx = (size_t)m * N + n;
        if constexpr (EPI == 1) {
          Cb[idx] = (bf16)v;
        } else if constexpr (EPI == 2) {
          atomicAdd(&Cf[idx], v);
        } else {
          float sv = v / (1.f + __expf(-1.702f * v));
          Cb[idx] = (bf16)sv;
        }
      }
    }
  }
}

// ---------------------------------------------------------------- attention
// Flash-style, block-diagonal segments [0,1024) and [1024,1280).
__global__ __launch_bounds__(256) void attn_kernel(const bf16* __restrict__ qkv,
                                                   bf16* __restrict__ o) {
  constexpr int QSTR = 104;
  constexpr int VSTR = 72;
  __shared__ bf16 Qs[64 * QSTR];
  __shared__ bf16 Ks[64 * QSTR];
  __shared__ bf16 Vt[80 * VSTR];
  __shared__ bf16 Ps[4 * 16 * 64];
  const int h = blockIdx.y;
  const int qt = blockIdx.x;  // 0..19
  const int q0 = qt * 64;
  const int kbeg = (q0 < 1024) ? 0 : 1024;
  const int kend = (q0 < 1024) ? 1024 : 1280;
  const int tid = threadIdx.x, wave = tid >> 6, lane = tid & 63;
  const int lm = lane & 15, quad = lane >> 4;

  for (int slot = tid; slot < 64 * 13; slot += 256) {
    int r = slot / 13, c = slot - r * 13;
    bf16x8_t val = {};
    if (c < 10) val = *(const bf16x8_t*)&qkv[(size_t)(q0 + r) * 3840 + h * 80 + c * 8];
    *(bf16x8_t*)&Qs[r * QSTR + c * 8] = val;
  }

  f32x4 oacc[5] = {};
  float mrow[4], lsum[4];
#pragma unroll
  for (int r = 0; r < 4; r++) { mrow[r] = -1e30f; lsum[r] = 0.f; }
  const float scale = 0.11180339887498949f;  // 1/sqrt(80)

  for (int t0 = kbeg; t0 < kend; t0 += 64) {
    __syncthreads();
    for (int slot = tid; slot < 64 * 13; slot += 256) {
      int r = slot / 13, c = slot - r * 13;
      bf16x8_t val = {};
      if (c < 10) val = *(const bf16x8_t*)&qkv[(size_t)(t0 + r) * 3840 + 1280 + h * 80 + c * 8];
      *(bf16x8_t*)&Ks[r * QSTR + c * 8] = val;
    }
    for (int slot = tid; slot < 64 * 10; slot += 256) {
      int r = slot / 10, c = slot - r * 10;
      bf16x8_t val = *(const bf16x8_t*)&qkv[(size_t)(t0 + r) * 3840 + 2560 + h * 80 + c * 8];
#pragma unroll
      for (int j = 0; j < 8; j++) Vt[(c * 8 + j) * VSTR + r] = val[j];
    }
    __syncthreads();

    f32x4 sc[4] = {};
#pragma unroll
    for (int ks = 0; ks < 3; ks++) {
      bf16x8_t aq = *(const bf16x8_t*)&Qs[(wave * 16 + lm) * QSTR + ks * 32 + quad * 8];
#pragma unroll
      for (int j = 0; j < 4; j++) {
        bf16x8_t bk = *(const bf16x8_t*)&Ks[(j * 16 + lm) * QSTR + ks * 32 + quad * 8];
        sc[j] = __builtin_amdgcn_mfma_f32_16x16x32_bf16(aq, bk, sc[j], 0, 0, 0);
      }
    }
#pragma unroll
    for (int j = 0; j < 4; j++) sc[j] *= scale;

    float alpha[4];
#pragma unroll
    for (int r = 0; r < 4; r++) {
      float mx = fmaxf(fmaxf(sc[0][r], sc[1][r]), fmaxf(sc[2][r], sc[3][r]));
#pragma unroll
      for (int off = 8; off; off >>= 1) mx = fmaxf(mx, __shfl_xor(mx, off));
      float mn = fmaxf(mrow[r], mx);
      alpha[r] = __expf(mrow[r] - mn);
      mrow[r] = mn;
      float rsum = 0.f;
#pragma unroll
      for (int j = 0; j < 4; j++) {
        float p = __expf(sc[j][r] - mn);
        sc[j][r] = p;
        rsum += p;
      }
#pragma unroll
      for (int off = 8; off; off >>= 1) rsum += __shfl_xor(rsum, off);
      lsum[r] = lsum[r] * alpha[r] + rsum;
    }

#pragma unroll
    for (int j = 0; j < 4; j++)
#pragma unroll
      for (int r = 0; r < 4; r++)
        Ps[wave * 1024 + (quad * 4 + r) * 64 + j * 16 + lm] = (bf16)sc[j][r];
#pragma unroll
    for (int jf = 0; jf < 5; jf++)
#pragma unroll
      for (int r = 0; r < 4; r++) oacc[jf][r] *= alpha[r];
    __syncthreads();

#pragma unroll
    for (int ks = 0; ks < 2; ks++) {
      bf16x8_t ap = *(const bf16x8_t*)&Ps[wave * 1024 + lm * 64 + ks * 32 + quad * 8];
#pragma unroll
      for (int jf = 0; jf < 5; jf++) {
        bf16x8_t bv = *(const bf16x8_t*)&Vt[(jf * 16 + lm) * VSTR + ks * 32 + quad * 8];
        oacc[jf] = __builtin_amdgcn_mfma_f32_16x16x32_bf16(ap, bv, oacc[jf], 0, 0, 0);
      }
    }
  }

#pragma unroll
  for (int jf = 0; jf < 5; jf++)
#pragma unroll
    for (int r = 0; r < 4; r++) {
      int q = q0 + wave * 16 + quad * 4 + r;
      int d = jf * 16 + lm;
      o[(size_t)q * DMODEL + h * 80 + d] = (bf16)(oacc[jf][r] / lsum[r]);
    }
}

// ---------------------------------------------------------------- driver
extern "C" void kernel_launch(void* const* d_in, const int* in_sizes, int n_in,
                              void* d_out, int out_size, void* d_ws, size_t ws_size,
                              hipStream_t stream) {
  const float* pixels = (const float*)d_in[0];
  const float* rotary = (const float*)d_in[1];
  const float* proj_w = (const float*)d_in[3];
  const float* ln1_w = (const float*)d_in[4];
  const float* ln1_b = (const float*)d_in[5];
  const float* qkv_w = (const float*)d_in[6];
  const float* qkv_b = (const float*)d_in[7];
  const float* po_w = (const float*)d_in[8];
  const float* po_b = (const float*)d_in[9];
  const float* ln2_w = (const float*)d_in[10];
  const float* ln2_b = (const float*)d_in[11];
  const float* fc1_w = (const float*)d_in[12];
  const float* fc1_b = (const float*)d_in[13];
  const float* fc2_w = (const float*)d_in[14];
  const float* fc2_b = (const float*)d_in[15];
  const float* mln_w = (const float*)d_in[16];
  const float* mln_b = (const float*)d_in[17];
  const float* m1_w = (const float*)d_in[18];
  const float* m1_b = (const float*)d_in[19];
  const float* m2_w = (const float*)d_in[20];
  const float* m2_b = (const float*)d_in[21];

  char* ws = (char*)d_ws;
  float* x = (float*)ws;   ws += (size_t)1280 * 1280 * 4;   // fp32 residual / m1 scratch (6.55MB)
  bf16* hb = (bf16*)ws;    ws += (size_t)1280 * 1280 * 2;   // LN out / attn out (3.28MB)
  bf16* shared = (bf16*)ws; ws += (size_t)1280 * 5120 * 2;  // 13.1MB shared region
  bf16* qkvb = shared;                 // 1280x3840
  bf16* h4b = shared;                  // 1280x5120
  bf16* ob = hb;
  bf16* padA = shared;                 // 1280x1280 (K padded to 1280)
  bf16* padW = shared + (size_t)1280 * 1280;
  // Optional fp32 scratch for split-K qkv/fc1 (26.2MB): qkvf (19.7) / h4f (26.2)
  float* fscr = (float*)ws;
  const bool big_ws = ws_size >= (size_t)49152000;

  dim3 blk(256);
  cvt_pad_kernel<<<(1280 * 1280) / 256, blk, 0, stream>>>(pixels, padA, 1280, 1176, 1280);
  cvt_pad_kernel<<<(1280 * 1280) / 256, blk, 0, stream>>>(proj_w, padW, 1280, 1176, 1280);
  zero_kernel<<<1600, blk, 0, stream>>>(x, 1280 * 1280 / 4);
  gemm_bt<2, bf16><<<dim3(10, 10, 4), blk, 0, stream>>>(padA, padW, nullptr, x, nullptr,
                                                        1280, 1280, 1280);

  for (int l = 0; l < 4; l++) {
    ln_kernel<<<1280, blk, 0, stream>>>(x, ln1_w + l * 1280, ln1_b + l * 1280, hb);
    if (big_ws) {
      zero_kernel<<<4800, blk, 0, stream>>>(fscr, 1280 * 3840 / 4);
      gemm_bt<2, float><<<dim3(10, 30, 2), blk, 0, stream>>>(hb, qkv_w + (size_t)l * 3840 * 1280,
                                                             nullptr, fscr, nullptr,
                                                             1280, 3840, 1280);
      qkv_epi_kernel<<<3200, blk, 0, stream>>>(fscr, qkv_b + l * 3840, rotary, qkvb);
    } else {
      gemm_bt<1, float><<<dim3(10, 30, 1), blk, 0, stream>>>(hb, qkv_w + (size_t)l * 3840 * 1280,
                                                             qkv_b + l * 3840, nullptr, qkvb,
                                                             1280, 3840, 1280);
      rope_kernel<<<(1280 * 16 * 40) / 256, blk, 0, stream>>>(qkvb, rotary);
    }
    attn_kernel<<<dim3(20, 16), blk, 0, stream>>>(qkvb, ob);
    gemm_bt<2, float><<<dim3(10, 10, 4), blk, 0, stream>>>(ob, po_w + (size_t)l * 1280 * 1280,
                                                           po_b + l * 1280, x, nullptr,
                                                           1280, 1280, 1280);
    ln_kernel<<<1280, blk, 0, stream>>>(x, ln2_w + l * 1280, ln2_b + l * 1280, hb);
    if (big_ws) {
      zero_kernel<<<6400, blk, 0, stream>>>(fscr, 1280 * 5120 / 4);
      gemm_bt<2, float><<<dim3(10, 40, 2), blk, 0, stream>>>(hb, fc1_w + (size_t)l * 5120 * 1280,
                                                             nullptr, fscr, nullptr,
                                                             1280, 5120, 1280);
      swish_cvt_kernel<<<6400, blk, 0, stream>>>(fscr, fc1_b + l * 5120, h4b,
                                                 1280 * 5120 / 4, 5120 / 4);
    } else {
      gemm_bt<3, float><<<dim3(10, 40, 1), blk, 0, stream>>>(hb, fc1_w + (size_t)l * 5120 * 1280,
                                                             fc1_b + l * 5120, nullptr, h4b,
                                                             1280, 5120, 1280);
    }
    gemm_bt<2, float><<<dim3(10, 10, 8), blk, 0, stream>>>(h4b, fc2_w + (size_t)l * 1280 * 5120,
                                                           fc2_b + l * 1280, x, nullptr,
                                                           1280, 1280, 5120);
  }

  ln_kernel<<<1280, blk, 0, stream>>>(x, mln_w, mln_b, hb);
  // x is dead now: reuse as m1 fp32 accumulator (320x5120)
  zero_kernel<<<1600, blk, 0, stream>>>(x, 320 * 5120 / 4);
  gemm_bt<2, float><<<dim3(3, 40, 8), blk, 0, stream>>>(hb, m1_w, m1_b, x, nullptr,
                                                        320, 5120, 5120);
  gelu_cvt_kernel<<<1600, blk, 0, stream>>>(x, h4b, 320 * 5120 / 4);
  zero_kernel<<<480, blk, 0, stream>>>((float*)d_out, 320 * 1536 / 4);
  gemm_bt<2, float><<<dim3(3, 12, 16), blk, 0, stream>>>(h4b, m2_w, m2_b, (float*)d_out, nullptr,
                                                         320, 1536, 5120);
}

// Round 5
// 1616.767 us; speedup vs baseline: 1.1694x; 1.1694x over previous
//
#include <hip/hip_runtime.h>
#include <hip/hip_bf16.h>

typedef __bf16 bf16;
typedef __bf16 bf16x8_t __attribute__((ext_vector_type(8)));
typedef __bf16 bf16x4_t __attribute__((ext_vector_type(4)));
typedef float f32x4 __attribute__((ext_vector_type(4)));

#define S_TOK 1280
#define DMODEL 1280

// ------------------------------------------------ fp32 -> bf16 convert + pad
__global__ __launch_bounds__(256) void cvt_pad_kernel(const float* __restrict__ src,
                                                      bf16* __restrict__ dst,
                                                      int rows, int scols, int dcols) {
  int idx = blockIdx.x * 256 + threadIdx.x;
  if (idx >= rows * dcols) return;
  int r = idx / dcols, c = idx - r * dcols;
  dst[idx] = (c < scols) ? (bf16)src[(size_t)r * scols + c] : (bf16)0.f;
}

// ---------------------------------------------------------------- zero fp32
__global__ __launch_bounds__(256) void zero_kernel(float* __restrict__ p, int n4) {
  int i = blockIdx.x * 256 + threadIdx.x;
  if (i < n4) ((float4*)p)[i] = make_float4(0.f, 0.f, 0.f, 0.f);
}

// ------------------------------------------------------- gelu(exact) -> bf16
__global__ __launch_bounds__(256) void gelu_cvt_kernel(const float* __restrict__ in,
                                                       bf16* __restrict__ out, int n4) {
  int i = blockIdx.x * 256 + threadIdx.x;
  if (i >= n4) return;
  float4 v = ((const float4*)in)[i];
  bf16x4_t o;
  o[0] = (bf16)(0.5f * v.x * (1.f + erff(v.x * 0.70710678f)));
  o[1] = (bf16)(0.5f * v.y * (1.f + erff(v.y * 0.70710678f)));
  o[2] = (bf16)(0.5f * v.z * (1.f + erff(v.z * 0.70710678f)));
  o[3] = (bf16)(0.5f * v.w * (1.f + erff(v.w * 0.70710678f)));
  *(bf16x4_t*)&out[(size_t)i * 4] = o;
}

// ---------------------------------------------------------------- layernorm
__global__ __launch_bounds__(256) void ln_kernel(const float* __restrict__ x,
                                                 const float* __restrict__ w,
                                                 const float* __restrict__ b,
                                                 bf16* __restrict__ out) {
  __shared__ float ls[4], ls2[4];
  int row = blockIdx.x;
  const float* xr = x + (size_t)row * DMODEL;
  float v[5];
  float s = 0.f, s2 = 0.f;
#pragma unroll
  for (int i = 0; i < 5; i++) {
    v[i] = xr[i * 256 + threadIdx.x];
    s += v[i];
    s2 += v[i] * v[i];
  }
#pragma unroll
  for (int off = 32; off; off >>= 1) {
    s += __shfl_down(s, off);
    s2 += __shfl_down(s2, off);
  }
  int wv = threadIdx.x >> 6;
  if ((threadIdx.x & 63) == 0) { ls[wv] = s; ls2[wv] = s2; }
  __syncthreads();
  float ts = ls[0] + ls[1] + ls[2] + ls[3];
  float ts2 = ls2[0] + ls2[1] + ls2[2] + ls2[3];
  float mu = ts * (1.f / DMODEL);
  float var = ts2 * (1.f / DMODEL) - mu * mu;
  float rstd = rsqrtf(var + 1e-6f);
#pragma unroll
  for (int i = 0; i < 5; i++) {
    int c = i * 256 + threadIdx.x;
    out[(size_t)row * DMODEL + c] = (bf16)((v[i] - mu) * rstd * w[c] + b[c]);
  }
}

// ---------------------------------------------------------------- rope
__global__ __launch_bounds__(256) void rope_kernel(bf16* __restrict__ qkv,
                                                   const float* __restrict__ rotary) {
  int idx = blockIdx.x * 256 + threadIdx.x;  // S*H*40
  if (idx >= S_TOK * 16 * 40) return;
  int d = idx % 40;
  int h = (idx / 40) & 15;
  int s = idx / (40 * 16);
  float ang = rotary[s * 40 + d];
  float c = cosf(ang), sn = sinf(ang);
#pragma unroll
  for (int qk = 0; qk < 2; ++qk) {
    bf16* base = qkv + (size_t)s * 3840 + qk * 1280 + h * 80;
    float t1 = (float)base[d], t2 = (float)base[d + 40];
    base[d] = (bf16)(t1 * c - t2 * sn);
    base[d + 40] = (bf16)(t2 * c + t1 * sn);
  }
}

// ---------------------------------------------------------------- GEMM
// C[m][n] = sum_k A[m][k] * B[n][k]  over this split's K-range.
// Split-K via blockIdx.z; bijective XCD swizzle (T1/m204) for L2 locality.
// EPI: 1 = bias -> bf16 store; if Vtb!=null, columns n>=2560 (the V part of
//          the qkv projection) are stored TRANSPOSED to Vtb[(n-2560)*1280+m]
//          instead (feeds attention's PV without an in-kernel transpose).
//      2 = atomicAdd into fp32 (bias added by bz==0 only)
//      3 = bias + x*sigmoid(1.702x) -> bf16
template <int EPI, typename TB>
__global__ __launch_bounds__(256, 2) void gemm_bt(const bf16* __restrict__ A,
                                                  const TB* __restrict__ B,
                                                  const float* __restrict__ bias,
                                                  float* __restrict__ Cf,
                                                  bf16* __restrict__ Cb,
                                                  bf16* __restrict__ Vtb,
                                                  int M, int N, int K) {
  constexpr int BKP = 40;  // padded LDS k-stride
  __shared__ bf16 As[128 * BKP];
  __shared__ bf16 Bs[128 * BKP];
  const int tid = threadIdx.x;

  unsigned nwg = gridDim.x * gridDim.y * gridDim.z;
  unsigned flat = blockIdx.x + gridDim.x * (blockIdx.y + gridDim.y * blockIdx.z);
  unsigned qq = nwg >> 3, rr = nwg & 7u;
  unsigned xcd = flat & 7u, off = flat >> 3;
  unsigned wg = (xcd < rr ? xcd * (qq + 1) : rr * (qq + 1) + (xcd - rr) * qq) + off;
  const int bm = wg % gridDim.x;
  const int bn = (wg / gridDim.x) % gridDim.y;
  const int bz = wg / (gridDim.x * gridDim.y);

  const int wave = tid >> 6, lane = tid & 63;
  const int wm = (wave & 1) << 6, wn = (wave >> 1) << 6;
  const int lm = lane & 15, quad = lane >> 4;
  f32x4 acc[4][4] = {};
  const int lrow = tid >> 2;       // 0..63
  const int lcol = (tid & 3) * 8;  // 0,8,16,24
  const int arow0 = bm * 128 + lrow;
  const int brow0 = bn * 128 + lrow;
  const int Kc = K / gridDim.z;
  const int kbeg = bz * Kc;
  const int kend = kbeg + Kc;

  for (int k0 = kbeg; k0 < kend; k0 += 32) {
#pragma unroll
    for (int p = 0; p < 2; p++) {
      int ar = arow0 + p * 64;
      if (ar > M - 1) ar = M - 1;  // clamp (excess rows never stored)
      *(bf16x8_t*)&As[(p * 64 + lrow) * BKP + lcol] =
          *(const bf16x8_t*)&A[(size_t)ar * K + k0 + lcol];
      if constexpr (sizeof(TB) == 2) {
        *(bf16x8_t*)&Bs[(p * 64 + lrow) * BKP + lcol] =
            *(const bf16x8_t*)&B[(size_t)(brow0 + p * 64) * K + k0 + lcol];
      } else {
        const float* bp = (const float*)&B[(size_t)(brow0 + p * 64) * K + k0 + lcol];
        float4 f0 = *(const float4*)bp;
        float4 f1 = *(const float4*)(bp + 4);
        bf16x8_t bv;
        bv[0] = (bf16)f0.x; bv[1] = (bf16)f0.y; bv[2] = (bf16)f0.z; bv[3] = (bf16)f0.w;
        bv[4] = (bf16)f1.x; bv[5] = (bf16)f1.y; bv[6] = (bf16)f1.z; bv[7] = (bf16)f1.w;
        *(bf16x8_t*)&Bs[(p * 64 + lrow) * BKP + lcol] = bv;
      }
    }
    __syncthreads();
    bf16x8_t af[4], bfv[4];
#pragma unroll
    for (int i = 0; i < 4; i++) {
      af[i] = *(const bf16x8_t*)&As[(wm + i * 16 + lm) * BKP + quad * 8];
      bfv[i] = *(const bf16x8_t*)&Bs[(wn + i * 16 + lm) * BKP + quad * 8];
    }
#pragma unroll
    for (int i = 0; i < 4; i++)
#pragma unroll
      for (int j = 0; j < 4; j++)
        acc[i][j] = __builtin_amdgcn_mfma_f32_16x16x32_bf16(af[i], bfv[j], acc[i][j], 0, 0, 0);
    __syncthreads();
  }

#pragma unroll
  for (int j = 0; j < 4; j++) {
    int n = bn * 128 + wn + j * 16 + lm;
    float bv = (bias != nullptr && bz == 0) ? bias[n] : 0.f;
#pragma unroll
    for (int i = 0; i < 4; i++) {
      int mbase = bm * 128 + wm + i * 16 + quad * 4;
      if (EPI == 1 && Vtb != nullptr && n >= 2560) {
        // transposed V store: 4 consecutive m for fixed n
        bf16x4_t pv;
#pragma unroll
        for (int r = 0; r < 4; r++) pv[r] = (bf16)(acc[i][j][r] + bv);
        *(bf16x4_t*)&Vtb[(size_t)(n - 2560) * 1280 + mbase] = pv;
        continue;
      }
#pragma unroll
      for (int r = 0; r < 4; r++) {
        int m = mbase + r;
        if (m >= M) continue;
        float v = acc[i][j][r] + bv;
        size_t idx = (size_t)m * N + n;
        if constexpr (EPI == 1) {
          Cb[idx] = (bf16)v;
        } else if constexpr (EPI == 2) {
          atomicAdd(&Cf[idx], v);
        } else {
          float sv = v / (1.f + __expf(-1.702f * v));
          Cb[idx] = (bf16)sv;
        }
      }
    }
  }
}

// ---------------------------------------------------------------- attention
// Flash-style, block-diagonal segments [0,1024) and [1024,1280).
// Split-K flash: 1088 blocks, each covering exactly 4 K-tiles of 64.
//   bid <  1024: seg0 job (sp = bid>>8 selects k-range sp*256..+256); writes
//                UNNORMALIZED partial O + (m,l) per row to opart/ml.
//   bid >= 1024: seg1 job (k-range 1024..1280); writes final O directly.
// V is consumed pre-transposed from vtb[h*80+d][t] (built by the qkv GEMM).
__global__ __launch_bounds__(256) void attn_kernel(const bf16* __restrict__ qkv,
                                                   const bf16* __restrict__ vtb,
                                                   bf16* __restrict__ o,
                                                   float* __restrict__ opart,
                                                   float* __restrict__ ml) {
  constexpr int QSTR = 104;  // k-stride for Qs/Ks (96 used, padded)
  constexpr int VSTR = 72;   // t-stride for Vt (64 used, padded; 16B-aligned rows)
  constexpr int PSTR = 72;   // k-stride for Ps (64 used; odd multiple of 8 -> spread banks)
  __shared__ bf16 Qs[64 * QSTR];
  __shared__ bf16 Ks[64 * QSTR];
  __shared__ bf16 Vt[80 * VSTR];
  __shared__ bf16 Ps[4 * 16 * PSTR];
  const int bid = blockIdx.x;
  int qt, h, kbeg;
  bool partial;
  if (bid < 1024) {
    int sp = bid >> 8, rem = bid & 255;
    h = rem >> 4; qt = rem & 15; kbeg = sp * 256; partial = true;
  } else {
    int j = bid - 1024;
    h = j >> 2; qt = 16 + (j & 3); kbeg = 1024; partial = false;
  }
  const int q0 = qt * 64;
  const int tid = threadIdx.x, wave = tid >> 6, lane = tid & 63;
  const int lm = lane & 15, quad = lane >> 4;

  // stage Q tile once (rows 64, 13 chunks of 8; chunks >= 10 are zero pad)
  for (int slot = tid; slot < 64 * 13; slot += 256) {
    int r = slot / 13, c = slot - r * 13;
    bf16x8_t val = {};
    if (c < 10) val = *(const bf16x8_t*)&qkv[(size_t)(q0 + r) * 3840 + h * 80 + c * 8];
    *(bf16x8_t*)&Qs[r * QSTR + c * 8] = val;
  }

  f32x4 oacc[5] = {};
  float mrow[4], lsum[4];
#pragma unroll
  for (int r = 0; r < 4; r++) { mrow[r] = -1e30f; lsum[r] = 0.f; }
  const float scale = 0.11180339887498949f;  // 1/sqrt(80)

  for (int tt = 0; tt < 4; ++tt) {
    const int t0 = kbeg + tt * 64;
    __syncthreads();
    // stage K tile (zero-padded to 96 k)
    for (int slot = tid; slot < 64 * 13; slot += 256) {
      int r = slot / 13, c = slot - r * 13;
      bf16x8_t val = {};
      if (c < 10) val = *(const bf16x8_t*)&qkv[(size_t)(t0 + r) * 3840 + 1280 + h * 80 + c * 8];
      *(bf16x8_t*)&Ks[r * QSTR + c * 8] = val;
    }
    // stage V^T (already transposed in global: vector copies, no scatter)
    for (int slot = tid; slot < 80 * 8; slot += 256) {
      int d = slot >> 3, c = slot & 7;
      *(bf16x8_t*)&Vt[d * VSTR + c * 8] =
          *(const bf16x8_t*)&vtb[(size_t)(h * 80 + d) * 1280 + t0 + c * 8];
    }
    __syncthreads();

    // scores: 16 q x 64 k per wave
    f32x4 sc[4] = {};
#pragma unroll
    for (int ks = 0; ks < 3; ks++) {
      bf16x8_t aq = *(const bf16x8_t*)&Qs[(wave * 16 + lm) * QSTR + ks * 32 + quad * 8];
#pragma unroll
      for (int j = 0; j < 4; j++) {
        bf16x8_t bk = *(const bf16x8_t*)&Ks[(j * 16 + lm) * QSTR + ks * 32 + quad * 8];
        sc[j] = __builtin_amdgcn_mfma_f32_16x16x32_bf16(aq, bk, sc[j], 0, 0, 0);
      }
    }
#pragma unroll
    for (int j = 0; j < 4; j++) sc[j] *= scale;

    // online softmax (row = quad*4 + r; 16 lanes of a quad share a row set)
    float alpha[4];
#pragma unroll
    for (int r = 0; r < 4; r++) {
      float mx = fmaxf(fmaxf(sc[0][r], sc[1][r]), fmaxf(sc[2][r], sc[3][r]));
#pragma unroll
      for (int off = 8; off; off >>= 1) mx = fmaxf(mx, __shfl_xor(mx, off));
      float mn = fmaxf(mrow[r], mx);
      alpha[r] = __expf(mrow[r] - mn);
      mrow[r] = mn;
      float rsum = 0.f;
#pragma unroll
      for (int j = 0; j < 4; j++) {
        float p = __expf(sc[j][r] - mn);
        sc[j][r] = p;
        rsum += p;
      }
#pragma unroll
      for (int off = 8; off; off >>= 1) rsum += __shfl_xor(rsum, off);
      lsum[r] = lsum[r] * alpha[r] + rsum;
    }

    // P -> LDS (per-wave region), rescale O
#pragma unroll
    for (int j = 0; j < 4; j++)
#pragma unroll
      for (int r = 0; r < 4; r++)
        Ps[wave * 16 * PSTR + (quad * 4 + r) * PSTR + j * 16 + lm] = (bf16)sc[j][r];
#pragma unroll
    for (int jf = 0; jf < 5; jf++)
#pragma unroll
      for (int r = 0; r < 4; r++) oacc[jf][r] *= alpha[r];
    __syncthreads();

    // PV: A = P (16x64), B = Vt (80x64), accumulate O (16q x 80d)
#pragma unroll
    for (int ks = 0; ks < 2; ks++) {
      bf16x8_t ap = *(const bf16x8_t*)&Ps[wave * 16 * PSTR + lm * PSTR + ks * 32 + quad * 8];
#pragma unroll
      for (int jf = 0; jf < 5; jf++) {
        bf16x8_t bv = *(const bf16x8_t*)&Vt[(jf * 16 + lm) * VSTR + ks * 32 + quad * 8];
        oacc[jf] = __builtin_amdgcn_mfma_f32_16x16x32_bf16(ap, bv, oacc[jf], 0, 0, 0);
      }
    }
  }

  if (partial) {
    // unnormalized partial O + per-row (m, l)
#pragma unroll
    for (int jf = 0; jf < 5; jf++)
#pragma unroll
      for (int r = 0; r < 4; r++) {
        int row = wave * 16 + quad * 4 + r;
        opart[(size_t)bid * 5120 + row * 80 + jf * 16 + lm] = oacc[jf][r];
      }
    if (lm == 0) {
#pragma unroll
      for (int r = 0; r < 4; r++) {
        int row = wave * 16 + quad * 4 + r;
        ml[bid * 128 + row * 2] = mrow[r];
        ml[bid * 128 + row * 2 + 1] = lsum[r];
      }
    }
  } else {
#pragma unroll
    for (int jf = 0; jf < 5; jf++)
#pragma unroll
      for (int r = 0; r < 4; r++) {
        int q = q0 + wave * 16 + quad * 4 + r;
        int d = jf * 16 + lm;
        o[(size_t)q * DMODEL + h * 80 + d] = (bf16)(oacc[jf][r] / lsum[r]);
      }
  }
}

// -------------------------------------------- merge 4 flash splits (seg0)
__global__ __launch_bounds__(256) void attn_merge_kernel(const float* __restrict__ opart,
                                                         const float* __restrict__ ml,
                                                         bf16* __restrict__ o) {
  int i = blockIdx.x * 256 + threadIdx.x;  // 16qt*16h*64q*20(d4) = 327680
  if (i >= 327680) return;
  int d4 = i % 20;
  int q = (i / 20) & 63;
  int h = (i / 1280) & 15;
  int qt = i / 20480;
  int jb = h * 16 + qt;
  float mm[4], llv[4];
#pragma unroll
  for (int s = 0; s < 4; s++) {
    mm[s] = ml[(s * 256 + jb) * 128 + q * 2];
    llv[s] = ml[(s * 256 + jb) * 128 + q * 2 + 1];
  }
  float mstar = fmaxf(fmaxf(mm[0], mm[1]), fmaxf(mm[2], mm[3]));
  float w[4], L = 0.f;
#pragma unroll
  for (int s = 0; s < 4; s++) {
    w[s] = __expf(mm[s] - mstar);
    L += llv[s] * w[s];
  }
  float4 acc = make_float4(0.f, 0.f, 0.f, 0.f);
#pragma unroll
  for (int s = 0; s < 4; s++) {
    const float4 v = *(const float4*)&opart[(size_t)(s * 256 + jb) * 5120 + q * 80 + d4 * 4];
    acc.x += w[s] * v.x; acc.y += w[s] * v.y; acc.z += w[s] * v.z; acc.w += w[s] * v.w;
  }
  float inv = 1.f / L;
  bf16x4_t ov;
  ov[0] = (bf16)(acc.x * inv); ov[1] = (bf16)(acc.y * inv);
  ov[2] = (bf16)(acc.z * inv); ov[3] = (bf16)(acc.w * inv);
  *(bf16x4_t*)&o[(size_t)(qt * 64 + q) * DMODEL + h * 80 + d4 * 4] = ov;
}

// ---------------------------------------------------------------- driver
extern "C" void kernel_launch(void* const* d_in, const int* in_sizes, int n_in,
                              void* d_out, int out_size, void* d_ws, size_t ws_size,
                              hipStream_t stream) {
  const float* pixels = (const float*)d_in[0];
  const float* rotary = (const float*)d_in[1];
  const float* proj_w = (const float*)d_in[3];
  const float* ln1_w = (const float*)d_in[4];
  const float* ln1_b = (const float*)d_in[5];
  const float* qkv_w = (const float*)d_in[6];
  const float* qkv_b = (const float*)d_in[7];
  const float* po_w = (const float*)d_in[8];
  const float* po_b = (const float*)d_in[9];
  const float* ln2_w = (const float*)d_in[10];
  const float* ln2_b = (const float*)d_in[11];
  const float* fc1_w = (const float*)d_in[12];
  const float* fc1_b = (const float*)d_in[13];
  const float* fc2_w = (const float*)d_in[14];
  const float* fc2_b = (const float*)d_in[15];
  const float* mln_w = (const float*)d_in[16];
  const float* mln_b = (const float*)d_in[17];
  const float* m1_w = (const float*)d_in[18];
  const float* m1_b = (const float*)d_in[19];
  const float* m2_w = (const float*)d_in[20];
  const float* m2_b = (const float*)d_in[21];

  char* ws = (char*)d_ws;
  float* x = (float*)ws;   ws += (size_t)1280 * 1280 * 4;   // fp32 residual / m1 scratch (6.55MB)
  bf16* hb = (bf16*)ws;    ws += (size_t)1280 * 1280 * 2;   // LN out / attn out (3.28MB)
  bf16* shared = (bf16*)ws; ws += (size_t)1280 * 5120 * 2;  // 13.1MB shared region
  bf16* qkvb = shared;                                   // 1280x3840 (q,k used; v slot unused)
  bf16* vtb = shared + (size_t)1280 * 3840;              // 1280x1280 V^T [h*80+d][t]
  bf16* h4b = shared;                                    // 1280x5120 (fc1 out, later phase)
  bf16* ob = hb;
  bf16* padA = shared;                                   // 1280x1280 (K padded to 1280)
  bf16* padW = shared + (size_t)1280 * 1280;
  // attn split-K partials (ws proven >= 49.15MB in round 4; need 44.4MB total)
  float* opart = (float*)ws;  ws += (size_t)1024 * 5120 * 4;  // 20.97MB
  float* mlbuf = (float*)ws;  ws += (size_t)1024 * 128 * 4;   // 0.52MB

  dim3 blk(256);
  cvt_pad_kernel<<<(1280 * 1280) / 256, blk, 0, stream>>>(pixels, padA, 1280, 1176, 1280);
  cvt_pad_kernel<<<(1280 * 1280) / 256, blk, 0, stream>>>(proj_w, padW, 1280, 1176, 1280);
  zero_kernel<<<1600, blk, 0, stream>>>(x, 1280 * 1280 / 4);
  gemm_bt<2, bf16><<<dim3(10, 10, 4), blk, 0, stream>>>(padA, padW, nullptr, x, nullptr,
                                                        nullptr, 1280, 1280, 1280);

  for (int l = 0; l < 4; l++) {
    ln_kernel<<<1280, blk, 0, stream>>>(x, ln1_w + l * 1280, ln1_b + l * 1280, hb);
    gemm_bt<1, float><<<dim3(10, 30, 1), blk, 0, stream>>>(hb, qkv_w + (size_t)l * 3840 * 1280,
                                                           qkv_b + l * 3840, nullptr, qkvb,
                                                           vtb, 1280, 3840, 1280);
    rope_kernel<<<(1280 * 16 * 40) / 256, blk, 0, stream>>>(qkvb, rotary);
    attn_kernel<<<1088, blk, 0, stream>>>(qkvb, vtb, ob, opart, mlbuf);
    attn_merge_kernel<<<1280, blk, 0, stream>>>(opart, mlbuf, ob);
    gemm_bt<2, float><<<dim3(10, 10, 4), blk, 0, stream>>>(ob, po_w + (size_t)l * 1280 * 1280,
                                                           po_b + l * 1280, x, nullptr,
                                                           nullptr, 1280, 1280, 1280);
    ln_kernel<<<1280, blk, 0, stream>>>(x, ln2_w + l * 1280, ln2_b + l * 1280, hb);
    gemm_bt<3, float><<<dim3(10, 40, 1), blk, 0, stream>>>(hb, fc1_w + (size_t)l * 5120 * 1280,
                                                           fc1_b + l * 5120, nullptr, h4b,
                                                           nullptr, 1280, 5120, 1280);
    gemm_bt<2, float><<<dim3(10, 10, 8), blk, 0, stream>>>(h4b, fc2_w + (size_t)l * 1280 * 5120,
                                                           fc2_b + l * 1280, x, nullptr,
                                                           nullptr, 1280, 1280, 5120);
  }

  ln_kernel<<<1280, blk, 0, stream>>>(x, mln_w, mln_b, hb);
  // x is dead now: reuse as m1 fp32 accumulator (320x5120)
  zero_kernel<<<1600, blk, 0, stream>>>(x, 320 * 5120 / 4);
  gemm_bt<2, float><<<dim3(3, 40, 8), blk, 0, stream>>>(hb, m1_w, m1_b, x, nullptr,
                                                        nullptr, 320, 5120, 5120);
  gelu_cvt_kernel<<<1600, blk, 0, stream>>>(x, h4b, 320 * 5120 / 4);
  zero_kernel<<<480, blk, 0, stream>>>((float*)d_out, 320 * 1536 / 4);
  gemm_bt<2, float><<<dim3(3, 12, 16), blk, 0, stream>>>(h4b, m2_w, m2_b, (float*)d_out, nullptr,
                                                         nullptr, 320, 1536, 5120);
}